// Round 1
// 397.788 us; speedup vs baseline: 1.1789x; 1.1789x over previous
//
#include <hip/hip_runtime.h>
#include <hip/hip_bf16.h>

constexpr int B  = 16;
constexpr int C  = 128;
constexpr int H  = 128;
constexpr int W  = 128;
constexpr int CO = 256;
constexpr int HO = 64;
constexpr int WO = 64;

#define EPSV   1e-8f
#define SLOPE  0.2f

typedef short bf16x8 __attribute__((ext_vector_type(8)));
typedef float f32x4  __attribute__((ext_vector_type(4)));

__device__ __forceinline__ short f2bs(float v) {
    __hip_bfloat16 h = __float2bfloat16(v);
    return *(short*)&h;
}
__device__ __forceinline__ float bs2f(short s) {
    __hip_bfloat16 h = *(__hip_bfloat16*)&s;
    return __bfloat162float(h);
}

// ---------------------------------------------------------------------------
// demod: d[conv][b][o] = rsqrt(sum_{i,k}(w[o,i,k]*(s[b,i]+1))^2 + eps)
// ---------------------------------------------------------------------------
__global__ __launch_bounds__(128) void demod_kernel(
    const float* __restrict__ w1, const float* __restrict__ w2,
    const float* __restrict__ s1, const float* __restrict__ s2,
    float* __restrict__ d)
{
    int bid  = blockIdx.x;          // conv*2048 + b*128 + o
    int conv = bid >> 11;
    int b    = (bid >> 7) & 15;
    int o    = bid & 127;
    const float* w = conv ? w2 : w1;
    const float* s = conv ? s2 : s1;
    int i = threadIdx.x;
    float sv = s[b * C + i] + 1.0f;
    const float* wp = w + (o * C + i) * 9;
    float sum = 0.f;
    #pragma unroll
    for (int k = 0; k < 9; ++k) { float t = wp[k] * sv; sum += t * t; }
    #pragma unroll
    for (int off = 32; off; off >>= 1) sum += __shfl_down(sum, off);
    __shared__ float red[2];
    if ((threadIdx.x & 63) == 0) red[threadIdx.x >> 6] = sum;
    __syncthreads();
    if (threadIdx.x == 0) d[bid] = rsqrtf(red[0] + red[1] + EPSV);
}

// ---------------------------------------------------------------------------
// expand -> wave-coalesced B-fragment tiling:
// wm[cb][tap][ocT=oc>>4][icC=ic>>5][(oc&15)*32 + (ic&31)]   (bf16)
// ---------------------------------------------------------------------------
__global__ __launch_bounds__(256) void expand_kernel(
    const float* __restrict__ w1, const float* __restrict__ w2,
    const float* __restrict__ s1, const float* __restrict__ s2,
    const float* __restrict__ d, short* __restrict__ wm)
{
    int idx = blockIdx.x * 256 + threadIdx.x;
    int ic  = idx & 127;
    int oc  = (idx >> 7) & 127;
    int t   = idx >> 14;            // cb*9+tap, < 288
    int tap = t % 9;
    int cb  = t / 9;                // conv*16+b
    int b   = cb & 15;
    int conv= cb >> 4;
    const float* w = conv ? w2 : w1;
    const float* s = conv ? s2 : s1;
    float v = w[(oc * C + ic) * 9 + tap] * (s[b * C + ic] + 1.0f)
            * d[(conv * B + b) * C + oc];
    int dst = cb * 147456
            + ((tap * 8 + (oc >> 4)) * 4 + (ic >> 5)) * 512
            + (oc & 15) * 32 + (ic & 31);
    wm[dst] = f2bs(v);
}

// ---------------------------------------------------------------------------
// dwexpand: dwm[tap][ocT=oc>>4 (16)][icC=ic>>5 (4)][(oc&15)*32+(ic&31)]
// ---------------------------------------------------------------------------
__global__ __launch_bounds__(256) void dwexpand_kernel(
    const float* __restrict__ dw, short* __restrict__ dwm)
{
    int idx = blockIdx.x * 256 + threadIdx.x;   // 16*256*128 = 524288
    int ic  = idx & 127;
    int oc  = (idx >> 7) & 255;
    int tap = idx >> 15;
    int dst = ((tap * 16 + (oc >> 4)) * 4 + (ic >> 5)) * 512
            + (oc & 15) * 32 + (ic & 31);
    dwm[dst] = f2bs(dw[(oc * C + ic) * 16 + tap]);
}

// ---------------------------------------------------------------------------
// nchw(f32) -> nhwc(bf16) transpose of features.
// ---------------------------------------------------------------------------
__global__ __launch_bounds__(256) void nchw2nhwc_kernel(
    const float* __restrict__ in, short* __restrict__ out)
{
    __shared__ short s[128 * 136];
    int bid = blockIdx.x;                   // b*128 + h
    int h = bid & 127, b = bid >> 7;
    int tid = threadIdx.x;
    for (int i = tid; i < 128 * 32; i += 256) {
        int w4 = i & 31, ic = i >> 5;
        float4 v = *(const float4*)&in[((b * C + ic) * H + h) * W + w4 * 4];
        s[(w4 * 4 + 0) * 136 + ic] = f2bs(v.x);
        s[(w4 * 4 + 1) * 136 + ic] = f2bs(v.y);
        s[(w4 * 4 + 2) * 136 + ic] = f2bs(v.z);
        s[(w4 * 4 + 3) * 136 + ic] = f2bs(v.w);
    }
    __syncthreads();
    for (int i = tid; i < 128 * 16; i += 256) {
        int icg = i & 15, w = i >> 4;
        *(uint4*)&out[((b * H + h) * W + w) * C + icg * 8] =
            *(uint4*)&s[w * 136 + icg * 8];
    }
}

// ---------------------------------------------------------------------------
// conv3x3 MFMA implicit GEMM, register-double-buffered K pipeline.
// block tile: 128 px (8h x 16w) x 128 oc; wave: 64 px x 64 oc.
// ---------------------------------------------------------------------------
__global__ __launch_bounds__(256, 3) void conv3x3_mfma(
    const short* __restrict__ in, const short* __restrict__ wmc,
    const short* __restrict__ res, short* __restrict__ out)
{
    __shared__ short sIn[10 * 18 * 136];   // 48,960 B

    int bid = blockIdx.x;
    int wt = bid & 7, ht = (bid >> 3) & 15, b = bid >> 7;
    int w0 = wt * 16, h0 = ht * 8;
    int tid  = threadIdx.x;
    int lane = tid & 63, wv = tid >> 6;
    int q = lane >> 4, l15 = lane & 15;
    int wr = wv & 1;       // row half
    int wc = wv >> 1;      // oc half

    for (int i = tid; i < 10 * 18 * 16; i += 256) {
        int icg = i & 15;
        int t = i >> 4;
        int wl = t % 18, hl = t / 18;
        int gh = h0 - 1 + hl, gw = w0 - 1 + wl;
        uint4 v = make_uint4(0u, 0u, 0u, 0u);
        if ((unsigned)gh < (unsigned)H && (unsigned)gw < (unsigned)W)
            v = *(const uint4*)&in[((b * H + gh) * W + gw) * C + icg * 8];
        *(uint4*)&sIn[(hl * 18 + wl) * 136 + icg * 8] = v;
    }
    __syncthreads();

    const short* wb = wmc + b * 147456;

    f32x4 acc[4][4];
    #pragma unroll
    for (int mt = 0; mt < 4; ++mt)
        #pragma unroll
        for (int nt = 0; nt < 4; ++nt)
            acc[mt][nt] = (f32x4){0.f, 0.f, 0.f, 0.f};

    bf16x8 af[2][4], bf[2][4];

    // prologue: (tap=0 -> dh=0,dw=0, c=0) into parity 0
    #pragma unroll
    for (int mt = 0; mt < 4; ++mt)
        af[0][mt] = *(const bf16x8*)&sIn[((wr * 4 + mt) * 18 + l15) * 136 + q * 8];
    #pragma unroll
    for (int nt = 0; nt < 4; ++nt)
        bf[0][nt] = *(const bf16x8*)&wb[((0 * 8 + wc * 4 + nt) * 4 + 0) * 512
                                        + l15 * 32 + q * 8];

    #pragma unroll 1
    for (int tap = 0; tap < 9; ++tap) {
        int dh  = tap / 3,  dwd = tap - dh * 3;
        int tapn = (tap + 1 < 9) ? tap + 1 : tap;   // dummy prefetch on last
        int dhn = tapn / 3, dwn = tapn - dhn * 3;
        #pragma unroll
        for (int c = 0; c < 4; ++c) {
            int p  = c & 1, pn = p ^ 1;
            int cn = (c + 1) & 3;
            int tE  = (c == 3) ? tapn : tap;
            int dhE = (c == 3) ? dhn : dh;
            int dwE = (c == 3) ? dwn : dwd;
            // prefetch step s+1
            #pragma unroll
            for (int mt = 0; mt < 4; ++mt)
                af[pn][mt] = *(const bf16x8*)&sIn[((wr * 4 + mt + dhE) * 18 + l15 + dwE) * 136
                                                  + cn * 32 + q * 8];
            #pragma unroll
            for (int nt = 0; nt < 4; ++nt)
                bf[pn][nt] = *(const bf16x8*)&wb[((tE * 8 + wc * 4 + nt) * 4 + cn) * 512
                                                 + l15 * 32 + q * 8];
            // compute step s
            #pragma unroll
            for (int mt = 0; mt < 4; ++mt)
                #pragma unroll
                for (int nt = 0; nt < 4; ++nt)
                    acc[mt][nt] = __builtin_amdgcn_mfma_f32_16x16x32_bf16(
                        af[p][mt], bf[p][nt], acc[mt][nt], 0, 0, 0);
        }
    }

    bool has_res = (res != nullptr);
    #pragma unroll
    for (int mt = 0; mt < 4; ++mt) {
        int h = h0 + wr * 4 + mt;
        #pragma unroll
        for (int nt = 0; nt < 4; ++nt) {
            int oc = wc * 64 + nt * 16 + l15;
            #pragma unroll
            for (int reg = 0; reg < 4; ++reg) {
                int w = w0 + q * 4 + reg;
                int idx = ((b * H + h) * W + w) * C + oc;
                float v = acc[mt][nt][reg];
                if (has_res) v += bs2f(res[idx]);
                v = v >= 0.f ? v : SLOPE * v;
                out[idx] = f2bs(v);
            }
        }
    }
}

// ---------------------------------------------------------------------------
// downconv MFMA v2 — conv3x3-shaped schedule.
// block tile: out 4oh x 16ow x ALL 256 oc; 4 waves, each 64 oc x 64 px.
// Input halo (10 ih x 34 iw) staged in LDS 64 ic at a time (2 stages,
// 43,520 B -> 3 blocks/CU). px-major LDS layout (128 B/px) with XOR slot
// swizzle (slot ^= (pix>>1)&7): conflict-free staging writes, ~2-way reads.
// Weights (A operand) stream from L2 with depth-1 register double-buffer,
// '#pragma unroll 1' tap loop — identical register shape to conv3x3.
// K = 16 taps x 4 ic-chunks = 64 steps x 16 MFMA/wave.
// ---------------------------------------------------------------------------
__global__ __launch_bounds__(256, 3) void downconv_mfma(
    const short* __restrict__ in, const short* __restrict__ dwm,
    const float* __restrict__ db, float* __restrict__ out)
{
    __shared__ short sIn[10 * 34 * 64];   // 43,520 B

    int bid = blockIdx.x;
    int wt = bid & 3;  bid >>= 2;
    int ht = bid & 15; bid >>= 4;
    int b  = bid;
    int ow0 = wt * 16, oh0 = ht * 4;
    int ih0 = 2 * oh0 - 1, iw0 = 2 * ow0 - 1;

    int tid  = threadIdx.x;
    int lane = tid & 63, wv = tid >> 6;   // wv = oc-quarter
    int q = lane >> 4, l15 = lane & 15;

    f32x4 acc[4][4];
    #pragma unroll
    for (int mt = 0; mt < 4; ++mt)
        #pragma unroll
        for (int nt = 0; nt < 4; ++nt)
            acc[mt][nt] = (f32x4){0.f, 0.f, 0.f, 0.f};

    #pragma unroll 1
    for (int s = 0; s < 2; ++s) {
        __syncthreads();               // protect sIn from prior-stage readers
        for (int i = tid; i < 10 * 34 * 8; i += 256) {
            int slot = i & 7, pix = i >> 3;
            int ihl = pix / 34, iwl = pix - ihl * 34;
            int gh = ih0 + ihl, gw = iw0 + iwl;
            uint4 v = make_uint4(0u, 0u, 0u, 0u);
            if ((unsigned)gh < (unsigned)H && (unsigned)gw < (unsigned)W)
                v = *(const uint4*)&in[((b * H + gh) * W + gw) * C + s * 64 + slot * 8];
            *(uint4*)&sIn[pix * 64 + ((slot ^ ((pix >> 1) & 7)) << 3)] = v;
        }
        __syncthreads();

        bf16x8 af[2][4], bf[2][4];
        // prologue: step 0 of this stage (tap 0: dh=0,dw=0; icC=0)
        #pragma unroll
        for (int mt = 0; mt < 4; ++mt)
            af[0][mt] = *(const bf16x8*)&dwm[((wv * 4 + mt) * 4 + s * 2) * 512
                                             + l15 * 32 + q * 8];
        #pragma unroll
        for (int nt = 0; nt < 4; ++nt) {
            int pix = (2 * nt) * 34 + 2 * l15;
            int sl  = q ^ ((pix >> 1) & 7);
            bf[0][nt] = *(const bf16x8*)&sIn[pix * 64 + sl * 8];
        }

        #pragma unroll 1
        for (int tap = 0; tap < 16; ++tap) {
            #pragma unroll
            for (int k = 0; k < 2; ++k) {          // icC within stage; parity = k
                int stepn = tap * 2 + k + 1;
                int tapn  = (stepn < 32) ? (stepn >> 1) : tap;   // dummy on last
                int kn    = (stepn < 32) ? (stepn & 1) : k;
                int dhn = tapn >> 2, dwn = tapn & 3;
                // prefetch next K-step
                #pragma unroll
                for (int mt = 0; mt < 4; ++mt)
                    af[k ^ 1][mt] = *(const bf16x8*)&dwm[((tapn * 16 + wv * 4 + mt) * 4
                                                          + s * 2 + kn) * 512
                                                         + l15 * 32 + q * 8];
                #pragma unroll
                for (int nt = 0; nt < 4; ++nt) {
                    int pix = (2 * nt + dhn) * 34 + dwn + 2 * l15;
                    int sl  = (kn * 4 + q) ^ ((pix >> 1) & 7);
                    bf[k ^ 1][nt] = *(const bf16x8*)&sIn[pix * 64 + sl * 8];
                }
                // compute current K-step
                #pragma unroll
                for (int mt = 0; mt < 4; ++mt)
                    #pragma unroll
                    for (int nt = 0; nt < 4; ++nt)
                        acc[mt][nt] = __builtin_amdgcn_mfma_f32_16x16x32_bf16(
                            af[k][mt], bf[k][nt], acc[mt][nt], 0, 0, 0);
            }
        }
    }

    // epilogue: D row = oc (q*4+reg within mt tile), col = ow (l15), nt = oh
    #pragma unroll
    for (int mt = 0; mt < 4; ++mt) {
        f32x4 bi = *(const f32x4*)&db[wv * 64 + mt * 16 + q * 4];
        #pragma unroll
        for (int nt = 0; nt < 4; ++nt) {
            int oh = oh0 + nt;
            #pragma unroll
            for (int reg = 0; reg < 4; ++reg) {
                int oc = wv * 64 + mt * 16 + q * 4 + reg;
                out[((b * CO + oc) * HO + oh) * WO + ow0 + l15] =
                    acc[mt][nt][reg] + bi[reg];
            }
        }
    }
}

// ---------------------------------------------------------------------------
extern "C" void kernel_launch(void* const* d_in, const int* in_sizes, int n_in,
                              void* d_out, int out_size, void* d_ws, size_t ws_size,
                              hipStream_t stream) {
    const float* features = (const float*)d_in[0];
    const float* sm1      = (const float*)d_in[1];   // style_mean1 -> s1
    const float* ss1      = (const float*)d_in[2];   // style_std1  -> s2 (per reference)
    const float* w1       = (const float*)d_in[6];
    const float* w2       = (const float*)d_in[7];
    const float* dw       = (const float*)d_in[8];
    const float* db       = (const float*)d_in[9];
    float* out = (float*)d_out;

    char* ws = (char*)d_ws;
    short* x1  = (short*)ws;                              // 67,108,864 B
    short* x2  = (short*)(ws + 67108864);                 // 67,108,864 B (also fx)
    short* wm  = (short*)(ws + 134217728);                // 9,437,184 B
    short* dwm = (short*)(ws + 143654912);                // 1,048,576 B
    float* dv  = (float*)(ws + 144703488);                // 16,384 B

    demod_kernel    <<<4096, 128, 0, stream>>>(w1, w2, sm1, ss1, dv);
    expand_kernel   <<<18432, 256, 0, stream>>>(w1, w2, sm1, ss1, dv, wm);
    dwexpand_kernel <<<2048, 256, 0, stream>>>(dw, dwm);
    nchw2nhwc_kernel<<<2048, 256, 0, stream>>>(features, x2);
    conv3x3_mfma    <<<2048, 256, 0, stream>>>(x2, wm, nullptr, x1);
    conv3x3_mfma    <<<2048, 256, 0, stream>>>(x1, wm + 16 * 147456, x1, x2);
    downconv_mfma   <<<1024, 256, 0, stream>>>(x2, dwm, db, out);
}